// Round 1
// baseline (1803.264 us; speedup 1.0000x reference)
//
#include <hip/hip_runtime.h>

// Problem constants
#define G 4
#define M 4096
#define D 128
#define NQ 16384            // queries per group
#define BS_TPD (NQ * G)     // 65536 total query rows

#define QT 64               // queries per block
#define MT 128              // m-chunk
#define KT 32               // k-chunk
#define XPAD 132            // 128 + 4 (keeps 16B alignment, banks rotate by 4/row)
#define EPAD 36             // 32 + 4

#define OFF_IND (BS_TPD * D)            // 8388608
#define OFF_CNT (OFF_IND + BS_TPD)      // 8454144

// --- Kernel 1: e2[g*M+m] = sum_d emb^2 (fp64) ---
__global__ __launch_bounds__(256) void e2_kernel(const float* __restrict__ emb,
                                                 double* __restrict__ e2) {
    int row  = blockIdx.x * 4 + (threadIdx.x >> 6);   // 16384 rows total
    int lane = threadIdx.x & 63;
    const float2 v = ((const float2*)(emb + (size_t)row * D))[lane];
    double s = (double)v.x * (double)v.x + (double)v.y * (double)v.y;
    #pragma unroll
    for (int off = 1; off < 64; off <<= 1) s += __shfl_xor(s, off, 64);
    if (lane == 0) e2[row] = s;
}

// --- Kernel 2: fused distance + argmin + index write + count histogram ---
__global__ __launch_bounds__(256) void argmin_kernel(const float* __restrict__ x,
                                                     const float* __restrict__ emb,
                                                     const double* __restrict__ e2,
                                                     float* __restrict__ out) {
    __shared__ float xs[QT][XPAD];      // 33792 B
    __shared__ float es[MT][EPAD];      // 18432 B

    const int g   = blockIdx.x >> 8;          // 256 blocks per group
    const int n0  = (blockIdx.x & 255) * QT;
    const int tid = threadIdx.x;
    const int tm  = tid & 15;                 // m-dim thread coord (0..15)
    const int tq  = tid >> 4;                 // q-dim thread coord (0..15)

    // Load x tile: 64 rows (query n0+r, group g) x 128 floats.
    // 2048 float4 total, 8 per thread; 32 lanes cover one row (512B contiguous).
    #pragma unroll
    for (int it = 0; it < 8; ++it) {
        int idx = it * 256 + tid;
        int r = idx >> 5, c = idx & 31;
        const float4 v = ((const float4*)(x + ((size_t)((n0 + r) * 4 + g)) * D))[c];
        *(float4*)&xs[r][c * 4] = v;
    }

    double best[4];
    int    bm[4];
    #pragma unroll
    for (int qi = 0; qi < 4; ++qi) { best[qi] = 1e300; bm[qi] = 0; }

    const double* e2g = e2 + (size_t)g * M;
    const float*  eg  = emb + (size_t)g * M * D;

    for (int mc = 0; mc < M / MT; ++mc) {
        const int m0 = mc * MT;
        double acc[4][8];
        #pragma unroll
        for (int qi = 0; qi < 4; ++qi)
            #pragma unroll
            for (int mi = 0; mi < 8; ++mi) acc[qi][mi] = 0.0;

        for (int kc = 0; kc < D / KT; ++kc) {
            __syncthreads();
            // Load e chunk: 128 rows x 32 floats = 1024 float4, 4 per thread.
            #pragma unroll
            for (int it = 0; it < 4; ++it) {
                int idx = it * 256 + tid;
                int r = idx >> 3, c = idx & 7;
                const float4 v =
                    ((const float4*)(eg + (size_t)(m0 + r) * D + kc * KT))[c];
                *(float4*)&es[r][c * 4] = v;
            }
            __syncthreads();

            #pragma unroll
            for (int kk = 0; kk < KT; kk += 4) {
                double xv[4][4];
                #pragma unroll
                for (int qi = 0; qi < 4; ++qi) {
                    const float4 v = *(const float4*)&xs[tq + 16 * qi][kc * KT + kk];
                    xv[qi][0] = v.x; xv[qi][1] = v.y;
                    xv[qi][2] = v.z; xv[qi][3] = v.w;
                }
                #pragma unroll
                for (int mi = 0; mi < 8; ++mi) {
                    const float4 v = *(const float4*)&es[tm + 16 * mi][kk];
                    const double e0 = v.x, e1 = v.y, e2v = v.z, e3 = v.w;
                    #pragma unroll
                    for (int qi = 0; qi < 4; ++qi) {
                        acc[qi][mi] = fma(xv[qi][0], e0,  acc[qi][mi]);
                        acc[qi][mi] = fma(xv[qi][1], e1,  acc[qi][mi]);
                        acc[qi][mi] = fma(xv[qi][2], e2v, acc[qi][mi]);
                        acc[qi][mi] = fma(xv[qi][3], e3,  acc[qi][mi]);
                    }
                }
            }
        }

        // Score and update running best (ascending m => strict < keeps lowest index)
        #pragma unroll
        for (int mi = 0; mi < 8; ++mi) {
            const int m = m0 + tm + 16 * mi;
            const double e2m = e2g[m];
            #pragma unroll
            for (int qi = 0; qi < 4; ++qi) {
                const double s = e2m - 2.0 * acc[qi][mi];
                if (s < best[qi]) { best[qi] = s; bm[qi] = m; }
            }
        }
    }

    // Cross-lane reduce over the 16 tm-lanes (lowest-index tie-break, numpy argmin)
    #pragma unroll
    for (int qi = 0; qi < 4; ++qi) {
        double v = best[qi];
        int    i = bm[qi];
        #pragma unroll
        for (int off = 1; off < 16; off <<= 1) {
            const double ov = __shfl_xor(v, off, 64);
            const int    oi = __shfl_xor(i, off, 64);
            if (ov < v || (ov == v && oi < i)) { v = ov; i = oi; }
        }
        if (tm == 0) {
            const int n = n0 + tq + 16 * qi;
            out[(size_t)OFF_IND + (size_t)n * 4 + g] = (float)i;
            atomicAdd(out + OFF_CNT + (size_t)g * M + i, 1.0f);
        }
    }
}

// --- Kernel 3: x_quant[n][g][:] = emb[g][idx][:] ---
__global__ __launch_bounds__(256) void gather_kernel(const float* __restrict__ emb,
                                                     const float* __restrict__ indf,
                                                     float* __restrict__ xq) {
    const int rid  = blockIdx.x * 8 + (threadIdx.x >> 5);  // 65536 rows (n*4+g)
    const int lane = threadIdx.x & 31;
    const int g = rid & 3;
    const int m = (int)indf[rid];
    const float4 v = ((const float4*)(emb + ((size_t)g * M + m) * D))[lane];
    ((float4*)(xq + (size_t)rid * D))[lane] = v;
}

extern "C" void kernel_launch(void* const* d_in, const int* in_sizes, int n_in,
                              void* d_out, int out_size, void* d_ws, size_t ws_size,
                              hipStream_t stream) {
    const float* x   = (const float*)d_in[0];
    const float* emb = (const float*)d_in[1];
    const float* cnt = (const float*)d_in[2];
    float*  out = (float*)d_out;
    double* e2  = (double*)d_ws;    // 16384 doubles = 128 KiB scratch

    hipLaunchKernelGGL(e2_kernel, dim3(16384 / 4), dim3(256), 0, stream, emb, e2);
    hipMemcpyAsync(out + OFF_CNT, cnt, (size_t)G * M * sizeof(float),
                   hipMemcpyDeviceToDevice, stream);
    hipLaunchKernelGGL(argmin_kernel, dim3((NQ / QT) * G), dim3(256), 0, stream,
                       x, emb, e2, out);
    hipLaunchKernelGGL(gather_kernel, dim3(BS_TPD / 8), dim3(256), 0, stream,
                       emb, out + OFF_IND, out);
}

// Round 2
// 368.394 us; speedup vs baseline: 4.8949x; 4.8949x over previous
//
#include <hip/hip_runtime.h>

// Problem constants
#define G 4
#define M 4096
#define D 128
#define NQ 16384
#define NROWS 65536                      // total query rows (NQ * G)
#define OFF_IND 8388608                  // NROWS * D
#define OFF_CNT (OFF_IND + NROWS)
#define DELTA 0.02f

typedef unsigned int u32;
typedef unsigned short u16;
typedef __attribute__((ext_vector_type(8))) short bf16x8;
typedef __attribute__((ext_vector_type(4))) float f32x4;

__device__ __forceinline__ u16 f2bf(float f) {
    u32 u = __float_as_uint(f);
    u32 r = (u + 0x7FFFu + ((u >> 16) & 1u)) >> 16;  // RNE
    return (u16)r;
}
__device__ __forceinline__ float bf2f(u16 b) { return __uint_as_float((u32)b << 16); }

// ---------------- new fast path ----------------

// xfrag layout (u32 units): ((qt*4 + ks)*2 + h)*256 + lane*4, 4 u32 (=8 bf16) per lane.
// qt = global query tile (g*1024 + n/16), ks = k-step (32 elems), h = hi/lo.
__global__ __launch_bounds__(256) void prep_x(const float* __restrict__ x,
                                              u32* __restrict__ xfrag) {
    const int tid = threadIdx.x, lane = tid & 63;
    const int c = blockIdx.x * 4 + (tid >> 6);      // 16384 chunks (qt,ks)
    const int ks = c & 3, qt = c >> 2;
    const int qrow = qt * 16 + (lane & 15);         // group-major query row
    const int g = qrow >> 14, n = qrow & 16383;
    const int k = ks * 32 + (lane >> 4) * 8;
    const float* src = x + ((size_t)n * 4 + g) * D + k;
    const float4 a = *(const float4*)src;
    const float4 b = *(const float4*)(src + 4);
    const float v[8] = {a.x, a.y, a.z, a.w, b.x, b.y, b.z, b.w};
    u32 hi[4], lo[4];
#pragma unroll
    for (int i = 0; i < 4; ++i) {
        const float v0 = -2.0f * v[2 * i], v1 = -2.0f * v[2 * i + 1];
        const u16 h0 = f2bf(v0), h1 = f2bf(v1);
        const u16 l0 = f2bf(v0 - bf2f(h0)), l1 = f2bf(v1 - bf2f(h1));
        hi[i] = (u32)h0 | ((u32)h1 << 16);
        lo[i] = (u32)l0 | ((u32)l1 << 16);
    }
    const u32 base = (u32)((qt * 4 + ks) * 2) * 256 + lane * 4;
    *(uint4*)(xfrag + base)       = make_uint4(hi[0], hi[1], hi[2], hi[3]);
    *(uint4*)(xfrag + base + 256) = make_uint4(lo[0], lo[1], lo[2], lo[3]);
}

// efrag layout: chunk = g*256+mt (16 m's); within chunk: ((ks*2+h)*256 + lane*4) u32.
__global__ __launch_bounds__(256) void prep_emb(const float* __restrict__ emb,
                                                u32* __restrict__ efrag) {
    const int tid = threadIdx.x, lane = tid & 63;
    const int c = blockIdx.x * 4 + (tid >> 6);      // 4096 chunks (g,mt,ks)
    const int ks = c & 3, mt = (c >> 2) & 255, g = c >> 10;
    const int m = mt * 16 + (lane & 15);
    const int k = ks * 32 + (lane >> 4) * 8;
    const float* src = emb + ((size_t)g * M + m) * D + k;
    const float4 a = *(const float4*)src;
    const float4 b = *(const float4*)(src + 4);
    const float v[8] = {a.x, a.y, a.z, a.w, b.x, b.y, b.z, b.w};
    u32 hi[4], lo[4];
#pragma unroll
    for (int i = 0; i < 4; ++i) {
        const float v0 = v[2 * i], v1 = v[2 * i + 1];
        const u16 h0 = f2bf(v0), h1 = f2bf(v1);
        const u16 l0 = f2bf(v0 - bf2f(h0)), l1 = f2bf(v1 - bf2f(h1));
        hi[i] = (u32)h0 | ((u32)h1 << 16);
        lo[i] = (u32)l0 | ((u32)l1 << 16);
    }
    const u32 base = (u32)(g * 256 + mt) * 2048 + (u32)(ks * 2) * 256 + lane * 4;
    *(uint4*)(efrag + base)       = make_uint4(hi[0], hi[1], hi[2], hi[3]);
    *(uint4*)(efrag + base + 256) = make_uint4(lo[0], lo[1], lo[2], lo[3]);
}

__global__ __launch_bounds__(256) void e2f_kernel(const float* __restrict__ emb,
                                                  float* __restrict__ e2f) {
    const int row = blockIdx.x * 4 + (threadIdx.x >> 6);
    const int lane = threadIdx.x & 63;
    const float2 v = ((const float2*)(emb + (size_t)row * D))[lane];
    double s = (double)v.x * (double)v.x + (double)v.y * (double)v.y;
#pragma unroll
    for (int off = 1; off < 64; off <<= 1) s += __shfl_xor(s, off, 64);
    if (lane == 0) e2f[row] = (float)s;
}

__global__ __launch_bounds__(256) void vq_mfma(const u32* __restrict__ xfrag,
                                               const u32* __restrict__ efrag,
                                               const float* __restrict__ e2f,
                                               float* __restrict__ out,
                                               int* __restrict__ flagcnt,
                                               int* __restrict__ flaglist) {
    __shared__ float e2s[M];          // 16 KB
    __shared__ u32 ebuf[2][2048];     // 2 x 8 KB double buffer

    const int tid = threadIdx.x, w = tid >> 6, lane = tid & 63;
    const int g = blockIdx.x >> 7, qb = blockIdx.x & 127;

    const float* e2g = e2f + (size_t)g * M;
    for (int i = tid; i < M / 4; i += 256) ((float4*)e2s)[i] = ((const float4*)e2g)[i];

    // x fragments: 2 query-tiles per wave, all K in registers
    const bf16x8* xp = (const bf16x8*)xfrag;
    const int qt0 = g * 1024 + qb * 8 + w * 2;
    bf16x8 xf[2][4][2];
#pragma unroll
    for (int f = 0; f < 2; ++f)
#pragma unroll
        for (int ks = 0; ks < 4; ++ks)
#pragma unroll
            for (int h = 0; h < 2; ++h)
                xf[f][ks][h] = xp[(size_t)(((qt0 + f) * 4 + ks) * 2 + h) * 64 + lane];

    float b1[8], b2[8];
    int i1[8];
#pragma unroll
    for (int s = 0; s < 8; ++s) { b1[s] = 3.4e38f; b2[s] = 3.4e38f; i1[s] = 0; }

    const uint4* eg = (const uint4*)(efrag + (size_t)g * 256 * 2048);
    // prologue: stage chunk 0
    {
        const uint4 s0 = eg[tid], s1 = eg[256 + tid];
        ((uint4*)ebuf[0])[tid] = s0;
        ((uint4*)ebuf[0])[256 + tid] = s1;
    }
    __syncthreads();

    int cur = 0;
    for (int mc = 0; mc < 256; ++mc) {
        uint4 s0, s1;
        const bool pf = (mc + 1 < 256);
        if (pf) {                     // T14: issue next-chunk loads early
            const uint4* src = eg + (size_t)(mc + 1) * 512;
            s0 = src[tid];
            s1 = src[256 + tid];
        }
        const bf16x8* bp = (const bf16x8*)ebuf[cur];
        bf16x8 bh[4], bl[4];
#pragma unroll
        for (int ks = 0; ks < 4; ++ks) {
            bh[ks] = bp[(ks * 2 + 0) * 64 + lane];
            bl[ks] = bp[(ks * 2 + 1) * 64 + lane];
        }
        f32x4 acc0 = {0.f, 0.f, 0.f, 0.f}, acc1 = {0.f, 0.f, 0.f, 0.f};
#pragma unroll
        for (int ks = 0; ks < 4; ++ks) {   // small terms first: Xlo*Ehi
            acc0 = __builtin_amdgcn_mfma_f32_16x16x32_bf16(xf[0][ks][1], bh[ks], acc0, 0, 0, 0);
            acc1 = __builtin_amdgcn_mfma_f32_16x16x32_bf16(xf[1][ks][1], bh[ks], acc1, 0, 0, 0);
        }
#pragma unroll
        for (int ks = 0; ks < 4; ++ks) {   // Xhi*Elo
            acc0 = __builtin_amdgcn_mfma_f32_16x16x32_bf16(xf[0][ks][0], bl[ks], acc0, 0, 0, 0);
            acc1 = __builtin_amdgcn_mfma_f32_16x16x32_bf16(xf[1][ks][0], bl[ks], acc1, 0, 0, 0);
        }
#pragma unroll
        for (int ks = 0; ks < 4; ++ks) {   // Xhi*Ehi
            acc0 = __builtin_amdgcn_mfma_f32_16x16x32_bf16(xf[0][ks][0], bh[ks], acc0, 0, 0, 0);
            acc1 = __builtin_amdgcn_mfma_f32_16x16x32_bf16(xf[1][ks][0], bh[ks], acc1, 0, 0, 0);
        }
        const int mcol = mc * 16 + (lane & 15);
        const float e2m = e2s[mcol];
#pragma unroll
        for (int r = 0; r < 4; ++r) {
            const float s0v = acc0[r] + e2m;
            b2[r] = fminf(b2[r], fmaxf(b1[r], s0v));
            i1[r] = (s0v < b1[r]) ? mcol : i1[r];
            b1[r] = fminf(b1[r], s0v);
            const float s1v = acc1[r] + e2m;
            b2[r + 4] = fminf(b2[r + 4], fmaxf(b1[r + 4], s1v));
            i1[r + 4] = (s1v < b1[r + 4]) ? mcol : i1[r + 4];
            b1[r + 4] = fminf(b1[r + 4], s1v);
        }
        if (pf) {                     // late LDS write of prefetched chunk
            uint4* dst = (uint4*)ebuf[cur ^ 1];
            dst[tid] = s0;
            dst[256 + tid] = s1;
        }
        __syncthreads();
        cur ^= 1;
    }

    // reduce across the 16 m-columns; tie-break lowest index
#pragma unroll
    for (int s = 0; s < 8; ++s) {
        float v1 = b1[s], v2 = b2[s];
        int j1 = i1[s];
#pragma unroll
        for (int off = 1; off < 16; off <<= 1) {
            const float o1 = __shfl_xor(v1, off, 64);
            const int   oj = __shfl_xor(j1, off, 64);
            const float o2 = __shfl_xor(v2, off, 64);
            v2 = fminf(fminf(v2, o2), fmaxf(v1, o1));
            if (o1 < v1 || (o1 == v1 && oj < j1)) { v1 = o1; j1 = oj; }
        }
        if ((lane & 15) == 0) {
            const int n = qb * 128 + w * 32 + (s >> 2) * 16 + (lane >> 4) * 4 + (s & 3);
            if (v2 - v1 > DELTA) {
                out[(size_t)OFF_IND + (size_t)n * 4 + g] = (float)j1;
                atomicAdd(out + OFF_CNT + (size_t)g * M + j1, 1.0f);
            } else {
                const int pos = atomicAdd(flagcnt, 1);
                if (pos < NROWS) flaglist[pos] = (g << 14) | n;
            }
        }
    }
}

// exact fp64 rescan for flagged (near-tie) queries
__global__ __launch_bounds__(256) void recheck(const float* __restrict__ x,
                                               const float* __restrict__ emb,
                                               const int* __restrict__ flagcnt,
                                               const int* __restrict__ flaglist,
                                               float* __restrict__ out) {
    __shared__ float xs[D];
    __shared__ double wv[4];
    __shared__ int wi[4];
    const int tid = threadIdx.x;
    int nf = *flagcnt;
    if (nf > NROWS) nf = NROWS;
    for (int it = blockIdx.x; it < nf; it += gridDim.x) {
        const int qid = flaglist[it];
        const int g = qid >> 14, n = qid & 16383;
        __syncthreads();
        if (tid < 32) ((float4*)xs)[tid] = ((const float4*)(x + ((size_t)n * 4 + g) * D))[tid];
        __syncthreads();
        double best = 1e300;
        int bi = 0;
        for (int j = 0; j < 16; ++j) {
            const int m = tid + j * 256;
            const float* e = emb + ((size_t)g * M + m) * D;
            double dot = 0.0, ee = 0.0;
            for (int k = 0; k < D; k += 4) {
                const float4 ev = *(const float4*)(e + k);
                const double e0 = ev.x, e1 = ev.y, e2v = ev.z, e3 = ev.w;
                dot = fma((double)xs[k + 0], e0, dot);
                dot = fma((double)xs[k + 1], e1, dot);
                dot = fma((double)xs[k + 2], e2v, dot);
                dot = fma((double)xs[k + 3], e3, dot);
                ee = fma(e0, e0, ee); ee = fma(e1, e1, ee);
                ee = fma(e2v, e2v, ee); ee = fma(e3, e3, ee);
            }
            const double s = ee - 2.0 * dot;
            if (s < best) { best = s; bi = m; }
        }
        for (int off = 1; off < 64; off <<= 1) {
            const double ob = __shfl_xor(best, off, 64);
            const int oi = __shfl_xor(bi, off, 64);
            if (ob < best || (ob == best && oi < bi)) { best = ob; bi = oi; }
        }
        if ((tid & 63) == 0) { wv[tid >> 6] = best; wi[tid >> 6] = bi; }
        __syncthreads();
        if (tid == 0) {
            double bv = wv[0];
            int bj = wi[0];
            for (int u = 1; u < 4; ++u)
                if (wv[u] < bv || (wv[u] == bv && wi[u] < bj)) { bv = wv[u]; bj = wi[u]; }
            out[(size_t)OFF_IND + (size_t)n * 4 + g] = (float)bj;
            atomicAdd(out + OFF_CNT + (size_t)g * M + bj, 1.0f);
        }
    }
}

__global__ __launch_bounds__(256) void gather_kernel(const float* __restrict__ emb,
                                                     const float* __restrict__ indf,
                                                     float* __restrict__ xq) {
    const int rid = blockIdx.x * 8 + (threadIdx.x >> 5);
    const int lane = threadIdx.x & 31;
    const int g = rid & 3;
    const int m = (int)indf[rid];
    const float4 v = ((const float4*)(emb + ((size_t)g * M + m) * D))[lane];
    ((float4*)(xq + (size_t)rid * D))[lane] = v;
}

// ---------------- fallback (round-0 exact fp64 path, used only if ws too small) ----------------

#define QT 64
#define MT 128
#define KT 32
#define XPAD 132
#define EPAD 36

__global__ __launch_bounds__(256) void e2d_kernel(const float* __restrict__ emb,
                                                  double* __restrict__ e2) {
    int row = blockIdx.x * 4 + (threadIdx.x >> 6);
    int lane = threadIdx.x & 63;
    const float2 v = ((const float2*)(emb + (size_t)row * D))[lane];
    double s = (double)v.x * (double)v.x + (double)v.y * (double)v.y;
#pragma unroll
    for (int off = 1; off < 64; off <<= 1) s += __shfl_xor(s, off, 64);
    if (lane == 0) e2[row] = s;
}

__global__ __launch_bounds__(256) void argmin_kernel(const float* __restrict__ x,
                                                     const float* __restrict__ emb,
                                                     const double* __restrict__ e2,
                                                     float* __restrict__ out) {
    __shared__ float xs[QT][XPAD];
    __shared__ float es[MT][EPAD];
    const int g = blockIdx.x >> 8;
    const int n0 = (blockIdx.x & 255) * QT;
    const int tid = threadIdx.x;
    const int tm = tid & 15;
    const int tq = tid >> 4;
#pragma unroll
    for (int it = 0; it < 8; ++it) {
        int idx = it * 256 + tid;
        int r = idx >> 5, c2 = idx & 31;
        const float4 v = ((const float4*)(x + ((size_t)((n0 + r) * 4 + g)) * D))[c2];
        *(float4*)&xs[r][c2 * 4] = v;
    }
    double best[4];
    int bm[4];
#pragma unroll
    for (int qi = 0; qi < 4; ++qi) { best[qi] = 1e300; bm[qi] = 0; }
    const double* e2g = e2 + (size_t)g * M;
    const float* eg = emb + (size_t)g * M * D;
    for (int mc = 0; mc < M / MT; ++mc) {
        const int m0 = mc * MT;
        double acc[4][8];
#pragma unroll
        for (int qi = 0; qi < 4; ++qi)
#pragma unroll
            for (int mi = 0; mi < 8; ++mi) acc[qi][mi] = 0.0;
        for (int kc = 0; kc < D / KT; ++kc) {
            __syncthreads();
#pragma unroll
            for (int it = 0; it < 4; ++it) {
                int idx = it * 256 + tid;
                int r = idx >> 3, c2 = idx & 7;
                const float4 v = ((const float4*)(eg + (size_t)(m0 + r) * D + kc * KT))[c2];
                *(float4*)&es[r][c2 * 4] = v;
            }
            __syncthreads();
#pragma unroll
            for (int kk = 0; kk < KT; kk += 4) {
                double xv[4][4];
#pragma unroll
                for (int qi = 0; qi < 4; ++qi) {
                    const float4 v = *(const float4*)&xs[tq + 16 * qi][kc * KT + kk];
                    xv[qi][0] = v.x; xv[qi][1] = v.y; xv[qi][2] = v.z; xv[qi][3] = v.w;
                }
#pragma unroll
                for (int mi = 0; mi < 8; ++mi) {
                    const float4 v = *(const float4*)&es[tm + 16 * mi][kk];
                    const double e0 = v.x, e1 = v.y, e2v = v.z, e3 = v.w;
#pragma unroll
                    for (int qi = 0; qi < 4; ++qi) {
                        acc[qi][mi] = fma(xv[qi][0], e0, acc[qi][mi]);
                        acc[qi][mi] = fma(xv[qi][1], e1, acc[qi][mi]);
                        acc[qi][mi] = fma(xv[qi][2], e2v, acc[qi][mi]);
                        acc[qi][mi] = fma(xv[qi][3], e3, acc[qi][mi]);
                    }
                }
            }
        }
#pragma unroll
        for (int mi = 0; mi < 8; ++mi) {
            const int m = m0 + tm + 16 * mi;
            const double e2m = e2g[m];
#pragma unroll
            for (int qi = 0; qi < 4; ++qi) {
                const double s = e2m - 2.0 * acc[qi][mi];
                if (s < best[qi]) { best[qi] = s; bm[qi] = m; }
            }
        }
    }
#pragma unroll
    for (int qi = 0; qi < 4; ++qi) {
        double v = best[qi];
        int i = bm[qi];
#pragma unroll
        for (int off = 1; off < 16; off <<= 1) {
            const double ov = __shfl_xor(v, off, 64);
            const int oi = __shfl_xor(i, off, 64);
            if (ov < v || (ov == v && oi < i)) { v = ov; i = oi; }
        }
        if (tm == 0) {
            const int n = n0 + tq + 16 * qi;
            out[(size_t)OFF_IND + (size_t)n * 4 + g] = (float)i;
            atomicAdd(out + OFF_CNT + (size_t)g * M + i, 1.0f);
        }
    }
}

// ---------------- launch ----------------

extern "C" void kernel_launch(void* const* d_in, const int* in_sizes, int n_in,
                              void* d_out, int out_size, void* d_ws, size_t ws_size,
                              hipStream_t stream) {
    const float* x   = (const float*)d_in[0];
    const float* emb = (const float*)d_in[1];
    const float* cnt = (const float*)d_in[2];
    float* out = (float*)d_out;

    if (ws_size >= 8716544) {
        u32*   efrag    = (u32*)d_ws;                          // 8,388,608 B
        float* e2fp     = (float*)((char*)d_ws + 8388608);     // 65,536 B
        int*   flagcnt  = (int*)((char*)d_ws + 8454144);       // 4 B
        int*   flaglist = (int*)((char*)d_ws + 8454400);       // 262,144 B
        u32*   xfrag    = (u32*)d_out;  // x_quant region reused as scratch (exact fit)

        hipLaunchKernelGGL(prep_x,   dim3(4096), dim3(256), 0, stream, x, xfrag);
        hipLaunchKernelGGL(prep_emb, dim3(1024), dim3(256), 0, stream, emb, efrag);
        hipLaunchKernelGGL(e2f_kernel, dim3(4096), dim3(256), 0, stream, emb, e2fp);
        hipMemcpyAsync(out + OFF_CNT, cnt, (size_t)G * M * sizeof(float),
                       hipMemcpyDeviceToDevice, stream);
        hipMemsetAsync(flagcnt, 0, 4, stream);
        hipLaunchKernelGGL(vq_mfma, dim3(512), dim3(256), 0, stream,
                           xfrag, efrag, e2fp, out, flagcnt, flaglist);
        hipLaunchKernelGGL(recheck, dim3(256), dim3(256), 0, stream,
                           x, emb, flagcnt, flaglist, out);
        hipLaunchKernelGGL(gather_kernel, dim3(NROWS / 8), dim3(256), 0, stream,
                           emb, out + OFF_IND, out);
    } else {
        double* e2 = (double*)d_ws;
        hipLaunchKernelGGL(e2d_kernel, dim3(4096), dim3(256), 0, stream, emb, e2);
        hipMemcpyAsync(out + OFF_CNT, cnt, (size_t)G * M * sizeof(float),
                       hipMemcpyDeviceToDevice, stream);
        hipLaunchKernelGGL(argmin_kernel, dim3((NQ / QT) * G), dim3(256), 0, stream,
                           x, emb, e2, out);
        hipLaunchKernelGGL(gather_kernel, dim3(NROWS / 8), dim3(256), 0, stream,
                           emb, out + OFF_IND, out);
    }
}

// Round 3
// 356.667 us; speedup vs baseline: 5.0559x; 1.0329x over previous
//
#include <hip/hip_runtime.h>

// Problem constants
#define G 4
#define M 4096
#define D 128
#define NQ 16384
#define NROWS 65536                      // total query rows (NQ * G)
#define OFF_IND 8388608                  // NROWS * D
#define OFF_CNT (OFF_IND + NROWS)
#define DELTA 0.02f

typedef unsigned int u32;
typedef unsigned short u16;
typedef __attribute__((ext_vector_type(8))) short bf16x8;
typedef __attribute__((ext_vector_type(4))) float f32x4;

__device__ __forceinline__ u16 f2bf(float f) {
    u32 u = __float_as_uint(f);
    return (u16)((u + 0x7FFFu + ((u >> 16) & 1u)) >> 16);  // RNE
}
__device__ __forceinline__ float bf2f(u16 b) { return __uint_as_float((u32)b << 16); }

union bfpack { bf16x8 v; u32 u[4]; };

// ---------------- fast path ----------------

// efrag layout: chunk = g*256 + mchunk (16 m's); within chunk: ((ks*2+h)*256 + lane*4) u32.
// Also accumulates e2f[g*M+m] (fp32 atomics; error ~1e-5 << DELTA, recheck-protected).
__global__ __launch_bounds__(256) void prep_emb_e2(const float* __restrict__ emb,
                                                   u32* __restrict__ efrag,
                                                   float* __restrict__ e2f) {
    const int tid = threadIdx.x, lane = tid & 63;
    const int c = blockIdx.x * 4 + (tid >> 6);      // 4096 chunks (g,mt,ks)
    const int ks = c & 3, mt = (c >> 2) & 255, g = c >> 10;
    const int m = mt * 16 + (lane & 15);
    const int k = ks * 32 + (lane >> 4) * 8;
    const float* src = emb + ((size_t)g * M + m) * D + k;
    const float4 a = *(const float4*)src;
    const float4 b = *(const float4*)(src + 4);
    const float v[8] = {a.x, a.y, a.z, a.w, b.x, b.y, b.z, b.w};
    float ss = 0.f;
#pragma unroll
    for (int i = 0; i < 8; ++i) ss = fmaf(v[i], v[i], ss);
    u32 hi[4], lo[4];
#pragma unroll
    for (int i = 0; i < 4; ++i) {
        const float v0 = v[2 * i], v1 = v[2 * i + 1];
        const u16 h0 = f2bf(v0), h1 = f2bf(v1);
        const u16 l0 = f2bf(v0 - bf2f(h0)), l1 = f2bf(v1 - bf2f(h1));
        hi[i] = (u32)h0 | ((u32)h1 << 16);
        lo[i] = (u32)l0 | ((u32)l1 << 16);
    }
    const u32 base = (u32)(g * 256 + mt) * 2048 + (u32)(ks * 2) * 256 + lane * 4;
    *(uint4*)(efrag + base)       = make_uint4(hi[0], hi[1], hi[2], hi[3]);
    *(uint4*)(efrag + base + 256) = make_uint4(lo[0], lo[1], lo[2], lo[3]);
    // e2 accumulation: lanes l, l+16, l+32, l+48 share m and cover the 32-k window
    ss += __shfl_xor(ss, 16, 64);
    ss += __shfl_xor(ss, 32, 64);
    if (lane < 16) atomicAdd(&e2f[g * M + m], ss);
}

// Split-m fused distance+argmin: block = (g,half) x 128 queries, scans 2048 m's.
__global__ __launch_bounds__(256) void vq_mfma2(const float* __restrict__ x,
                                                const u32* __restrict__ efrag,
                                                const float* __restrict__ e2f,
                                                float* __restrict__ pb1,
                                                float* __restrict__ pb2,
                                                int* __restrict__ pi1) {
    __shared__ float e2s[2048];       // 8 KB
    __shared__ u32 ebuf[2][2048];     // 2 x 8 KB double buffer

    const int tid = threadIdx.x, w = tid >> 6, lane = tid & 63;
    const int combo = blockIdx.x & 7;              // -> XCD c (round-robin dispatch)
    const int g = combo >> 1, half = combo & 1;
    const int qb = blockIdx.x >> 3;                // 0..127

    const float* e2g = e2f + (size_t)g * M + half * 2048;
    for (int i = tid; i < 512; i += 256) ((float4*)e2s)[i] = ((const float4*)e2g)[i];

    // Load + convert this wave's 2 query-tiles (32 queries) straight from x.
    const int qt0 = qb * 8 + w * 2;                // local query-tile within group
    bf16x8 xf[2][4][2];
#pragma unroll
    for (int f = 0; f < 2; ++f) {
        const int n = (qt0 + f) * 16 + (lane & 15);
#pragma unroll
        for (int ks = 0; ks < 4; ++ks) {
            const int k = ks * 32 + (lane >> 4) * 8;
            const float* src = x + ((size_t)n * 4 + g) * D + k;
            const float4 a = *(const float4*)src;
            const float4 b = *(const float4*)(src + 4);
            const float v[8] = {a.x, a.y, a.z, a.w, b.x, b.y, b.z, b.w};
            bfpack ph, pl;
#pragma unroll
            for (int i = 0; i < 4; ++i) {
                const float v0 = -2.0f * v[2 * i], v1 = -2.0f * v[2 * i + 1];
                const u16 h0 = f2bf(v0), h1 = f2bf(v1);
                const u16 l0 = f2bf(v0 - bf2f(h0)), l1 = f2bf(v1 - bf2f(h1));
                ph.u[i] = (u32)h0 | ((u32)h1 << 16);
                pl.u[i] = (u32)l0 | ((u32)l1 << 16);
            }
            xf[f][ks][0] = ph.v;
            xf[f][ks][1] = pl.v;
        }
    }

    float b1[8], b2[8];
    int i1[8];
#pragma unroll
    for (int s = 0; s < 8; ++s) { b1[s] = 3.4e38f; b2[s] = 3.4e38f; i1[s] = 0; }

    const uint4* eg = (const uint4*)(efrag + (size_t)(g * 256 + half * 128) * 2048);
    {
        const uint4 s0 = eg[tid], s1 = eg[256 + tid];
        ((uint4*)ebuf[0])[tid] = s0;
        ((uint4*)ebuf[0])[256 + tid] = s1;
    }
    __syncthreads();

    int cur = 0;
    const int mb0 = half * 2048;
    for (int mc = 0; mc < 128; ++mc) {
        uint4 s0, s1;
        const bool pf = (mc + 1 < 128);
        if (pf) {                     // issue next-chunk loads early (T14)
            const uint4* src = eg + (size_t)(mc + 1) * 512;
            s0 = src[tid];
            s1 = src[256 + tid];
        }
        const bf16x8* bp = (const bf16x8*)ebuf[cur];
        bf16x8 bh[4], bl[4];
#pragma unroll
        for (int ks = 0; ks < 4; ++ks) {
            bh[ks] = bp[(ks * 2 + 0) * 64 + lane];
            bl[ks] = bp[(ks * 2 + 1) * 64 + lane];
        }
        const int mcol = mb0 + mc * 16 + (lane & 15);
        const float e2c = e2s[mc * 16 + (lane & 15)];
        const f32x4 init = {e2c, e2c, e2c, e2c};   // fold e2[m] into C-operand
        f32x4 acc0, acc1;
        acc0 = __builtin_amdgcn_mfma_f32_16x16x32_bf16(xf[0][0][1], bh[0], init, 0, 0, 0);
        acc1 = __builtin_amdgcn_mfma_f32_16x16x32_bf16(xf[1][0][1], bh[0], init, 0, 0, 0);
#pragma unroll
        for (int ks = 1; ks < 4; ++ks) {           // Xlo*Ehi (small terms first)
            acc0 = __builtin_amdgcn_mfma_f32_16x16x32_bf16(xf[0][ks][1], bh[ks], acc0, 0, 0, 0);
            acc1 = __builtin_amdgcn_mfma_f32_16x16x32_bf16(xf[1][ks][1], bh[ks], acc1, 0, 0, 0);
        }
#pragma unroll
        for (int ks = 0; ks < 4; ++ks) {           // Xhi*Elo
            acc0 = __builtin_amdgcn_mfma_f32_16x16x32_bf16(xf[0][ks][0], bl[ks], acc0, 0, 0, 0);
            acc1 = __builtin_amdgcn_mfma_f32_16x16x32_bf16(xf[1][ks][0], bl[ks], acc1, 0, 0, 0);
        }
#pragma unroll
        for (int ks = 0; ks < 4; ++ks) {           // Xhi*Ehi
            acc0 = __builtin_amdgcn_mfma_f32_16x16x32_bf16(xf[0][ks][0], bh[ks], acc0, 0, 0, 0);
            acc1 = __builtin_amdgcn_mfma_f32_16x16x32_bf16(xf[1][ks][0], bh[ks], acc1, 0, 0, 0);
        }
#pragma unroll
        for (int r = 0; r < 4; ++r) {
            const float s0v = acc0[r];
            b2[r] = fminf(b2[r], fmaxf(b1[r], s0v));
            i1[r] = (s0v < b1[r]) ? mcol : i1[r];
            b1[r] = fminf(b1[r], s0v);
            const float s1v = acc1[r];
            b2[r + 4] = fminf(b2[r + 4], fmaxf(b1[r + 4], s1v));
            i1[r + 4] = (s1v < b1[r + 4]) ? mcol : i1[r + 4];
            b1[r + 4] = fminf(b1[r + 4], s1v);
        }
        if (pf) {                     // late LDS write of prefetched chunk
            uint4* dst = (uint4*)ebuf[cur ^ 1];
            dst[tid] = s0;
            dst[256 + tid] = s1;
        }
        __syncthreads();
        cur ^= 1;
    }

    // reduce across 16 m-columns; lowest-index tie-break; write partials
#pragma unroll
    for (int s = 0; s < 8; ++s) {
        float v1 = b1[s], v2 = b2[s];
        int j1 = i1[s];
#pragma unroll
        for (int off = 1; off < 16; off <<= 1) {
            const float o1 = __shfl_xor(v1, off, 64);
            const int   oj = __shfl_xor(j1, off, 64);
            const float o2 = __shfl_xor(v2, off, 64);
            v2 = fminf(fminf(v2, o2), fmaxf(v1, o1));
            if (o1 < v1 || (o1 == v1 && oj < j1)) { v1 = o1; j1 = oj; }
        }
        if ((lane & 15) == 0) {
            const int n = (qt0 + (s >> 2)) * 16 + (lane >> 4) * 4 + (s & 3);
            const int pidx = ((((g << 14) | n)) << 1) | half;
            pb1[pidx] = v1;
            pb2[pidx] = v2;
            pi1[pidx] = j1;
        }
    }
}

// Combine the two m-halves per query; write index+count or flag for recheck.
__global__ __launch_bounds__(256) void merge_kernel(const float* __restrict__ pb1,
                                                    const float* __restrict__ pb2,
                                                    const int* __restrict__ pi1,
                                                    float* __restrict__ out,
                                                    int* __restrict__ flagcnt,
                                                    int* __restrict__ flaglist) {
    const int t = blockIdx.x * 256 + threadIdx.x;   // (g<<14)|n
    const float v1a = pb1[2 * t], v1b = pb1[2 * t + 1];
    const float v2a = pb2[2 * t], v2b = pb2[2 * t + 1];
    const int   ia = pi1[2 * t],  ib = pi1[2 * t + 1];
    const float v1 = fminf(v1a, v1b);
    const int   i  = (v1b < v1a) ? ib : ia;         // tie -> half0 (lower index)
    const float v2 = fminf(fminf(v2a, v2b), fmaxf(v1a, v1b));
    const int g = t >> 14, n = t & 16383;
    if (v2 - v1 > DELTA) {
        out[(size_t)OFF_IND + (size_t)n * 4 + g] = (float)i;
        atomicAdd(out + OFF_CNT + (size_t)g * M + i, 1.0f);
    } else {
        const int pos = atomicAdd(flagcnt, 1);
        flaglist[pos] = t;
    }
}

// exact fp64 rescan for flagged (near-tie) queries; one query per block
__global__ __launch_bounds__(256) void recheck(const float* __restrict__ x,
                                               const float* __restrict__ emb,
                                               const int* __restrict__ flagcnt,
                                               const int* __restrict__ flaglist,
                                               float* __restrict__ out) {
    __shared__ float xs[D];
    __shared__ double wv[4];
    __shared__ int wi[4];
    const int tid = threadIdx.x;
    int nf = *flagcnt;
    if (nf > NROWS) nf = NROWS;
    for (int it = blockIdx.x; it < nf; it += gridDim.x) {
        const int qid = flaglist[it];
        const int g = qid >> 14, n = qid & 16383;
        __syncthreads();
        if (tid < 32) ((float4*)xs)[tid] = ((const float4*)(x + ((size_t)n * 4 + g) * D))[tid];
        __syncthreads();
        double best = 1e300;
        int bi = 0;
        for (int j = 0; j < 16; ++j) {
            const int m = tid + j * 256;
            const float* e = emb + ((size_t)g * M + m) * D;
            double dot = 0.0, ee = 0.0;
            for (int k = 0; k < D; k += 4) {
                const float4 ev = *(const float4*)(e + k);
                const double e0 = ev.x, e1 = ev.y, e2v = ev.z, e3 = ev.w;
                dot = fma((double)xs[k + 0], e0, dot);
                dot = fma((double)xs[k + 1], e1, dot);
                dot = fma((double)xs[k + 2], e2v, dot);
                dot = fma((double)xs[k + 3], e3, dot);
                ee = fma(e0, e0, ee); ee = fma(e1, e1, ee);
                ee = fma(e2v, e2v, ee); ee = fma(e3, e3, ee);
            }
            const double s = ee - 2.0 * dot;
            if (s < best) { best = s; bi = m; }
        }
        for (int off = 1; off < 64; off <<= 1) {
            const double ob = __shfl_xor(best, off, 64);
            const int oi = __shfl_xor(bi, off, 64);
            if (ob < best || (ob == best && oi < bi)) { best = ob; bi = oi; }
        }
        if ((tid & 63) == 0) { wv[tid >> 6] = best; wi[tid >> 6] = bi; }
        __syncthreads();
        if (tid == 0) {
            double bv = wv[0];
            int bj = wi[0];
            for (int u = 1; u < 4; ++u)
                if (wv[u] < bv || (wv[u] == bv && wi[u] < bj)) { bv = wv[u]; bj = wi[u]; }
            out[(size_t)OFF_IND + (size_t)n * 4 + g] = (float)bj;
            atomicAdd(out + OFF_CNT + (size_t)g * M + bj, 1.0f);
        }
    }
}

__global__ __launch_bounds__(256) void gather_kernel(const float* __restrict__ emb,
                                                     const float* __restrict__ indf,
                                                     float* __restrict__ xq) {
    const int rid = blockIdx.x * 8 + (threadIdx.x >> 5);
    const int lane = threadIdx.x & 31;
    const int g = rid & 3;
    const int m = (int)indf[rid];
    const float4 v = ((const float4*)(emb + ((size_t)g * M + m) * D))[lane];
    ((float4*)(xq + (size_t)rid * D))[lane] = v;
}

// ---------------- fallback (exact fp64 path, used only if ws too small) ----------------

#define QT 64
#define MT 128
#define KT 32
#define XPAD 132
#define EPAD 36

__global__ __launch_bounds__(256) void e2d_kernel(const float* __restrict__ emb,
                                                  double* __restrict__ e2) {
    int row = blockIdx.x * 4 + (threadIdx.x >> 6);
    int lane = threadIdx.x & 63;
    const float2 v = ((const float2*)(emb + (size_t)row * D))[lane];
    double s = (double)v.x * (double)v.x + (double)v.y * (double)v.y;
#pragma unroll
    for (int off = 1; off < 64; off <<= 1) s += __shfl_xor(s, off, 64);
    if (lane == 0) e2[row] = s;
}

__global__ __launch_bounds__(256) void argmin_kernel(const float* __restrict__ x,
                                                     const float* __restrict__ emb,
                                                     const double* __restrict__ e2,
                                                     float* __restrict__ out) {
    __shared__ float xs[QT][XPAD];
    __shared__ float es[MT][EPAD];
    const int g = blockIdx.x >> 8;
    const int n0 = (blockIdx.x & 255) * QT;
    const int tid = threadIdx.x;
    const int tm = tid & 15;
    const int tq = tid >> 4;
#pragma unroll
    for (int it = 0; it < 8; ++it) {
        int idx = it * 256 + tid;
        int r = idx >> 5, c2 = idx & 31;
        const float4 v = ((const float4*)(x + ((size_t)((n0 + r) * 4 + g)) * D))[c2];
        *(float4*)&xs[r][c2 * 4] = v;
    }
    double best[4];
    int bm[4];
#pragma unroll
    for (int qi = 0; qi < 4; ++qi) { best[qi] = 1e300; bm[qi] = 0; }
    const double* e2g = e2 + (size_t)g * M;
    const float* eg = emb + (size_t)g * M * D;
    for (int mc = 0; mc < M / MT; ++mc) {
        const int m0 = mc * MT;
        double acc[4][8];
#pragma unroll
        for (int qi = 0; qi < 4; ++qi)
#pragma unroll
            for (int mi = 0; mi < 8; ++mi) acc[qi][mi] = 0.0;
        for (int kc = 0; kc < D / KT; ++kc) {
            __syncthreads();
#pragma unroll
            for (int it = 0; it < 4; ++it) {
                int idx = it * 256 + tid;
                int r = idx >> 3, c2 = idx & 7;
                const float4 v = ((const float4*)(eg + (size_t)(m0 + r) * D + kc * KT))[c2];
                *(float4*)&es[r][c2 * 4] = v;
            }
            __syncthreads();
#pragma unroll
            for (int kk = 0; kk < KT; kk += 4) {
                double xv[4][4];
#pragma unroll
                for (int qi = 0; qi < 4; ++qi) {
                    const float4 v = *(const float4*)&xs[tq + 16 * qi][kc * KT + kk];
                    xv[qi][0] = v.x; xv[qi][1] = v.y; xv[qi][2] = v.z; xv[qi][3] = v.w;
                }
#pragma unroll
                for (int mi = 0; mi < 8; ++mi) {
                    const float4 v = *(const float4*)&es[tm + 16 * mi][kk];
                    const double e0 = v.x, e1 = v.y, e2v = v.z, e3 = v.w;
#pragma unroll
                    for (int qi = 0; qi < 4; ++qi) {
                        acc[qi][mi] = fma(xv[qi][0], e0, acc[qi][mi]);
                        acc[qi][mi] = fma(xv[qi][1], e1, acc[qi][mi]);
                        acc[qi][mi] = fma(xv[qi][2], e2v, acc[qi][mi]);
                        acc[qi][mi] = fma(xv[qi][3], e3, acc[qi][mi]);
                    }
                }
            }
        }
#pragma unroll
        for (int mi = 0; mi < 8; ++mi) {
            const int m = m0 + tm + 16 * mi;
            const double e2m = e2g[m];
#pragma unroll
            for (int qi = 0; qi < 4; ++qi) {
                const double s = e2m - 2.0 * acc[qi][mi];
                if (s < best[qi]) { best[qi] = s; bm[qi] = m; }
            }
        }
    }
#pragma unroll
    for (int qi = 0; qi < 4; ++qi) {
        double v = best[qi];
        int i = bm[qi];
#pragma unroll
        for (int off = 1; off < 16; off <<= 1) {
            const double ov = __shfl_xor(v, off, 64);
            const int oi = __shfl_xor(i, off, 64);
            if (ov < v || (ov == v && oi < i)) { v = ov; i = oi; }
        }
        if (tm == 0) {
            const int n = n0 + tq + 16 * qi;
            out[(size_t)OFF_IND + (size_t)n * 4 + g] = (float)i;
            atomicAdd(out + OFF_CNT + (size_t)g * M + i, 1.0f);
        }
    }
}

// ---------------- launch ----------------

extern "C" void kernel_launch(void* const* d_in, const int* in_sizes, int n_in,
                              void* d_out, int out_size, void* d_ws, size_t ws_size,
                              hipStream_t stream) {
    const float* x   = (const float*)d_in[0];
    const float* emb = (const float*)d_in[1];
    const float* cnt = (const float*)d_in[2];
    float* out = (float*)d_out;

    if (ws_size >= 8716544) {
        u32*   efrag    = (u32*)d_ws;                          // [0, 8388608)
        float* e2fp     = (float*)((char*)d_ws + 8388608);     // 64 KB
        int*   flagcnt  = (int*)((char*)d_ws + 8454144);       // 4 B (pad 256)
        int*   flaglist = (int*)((char*)d_ws + 8454400);       // 256 KB
        // partials live in the out-buffer's x_quant region (overwritten by gather later)
        float* pb1 = out;                                      // 131072 f32
        float* pb2 = out + 131072;
        int*   pi1 = (int*)(out + 262144);

        hipMemsetAsync((char*)d_ws + 8388608, 0, 65792, stream);  // e2f + flagcnt
        hipLaunchKernelGGL(prep_emb_e2, dim3(1024), dim3(256), 0, stream, emb, efrag, e2fp);
        hipMemcpyAsync(out + OFF_CNT, cnt, (size_t)G * M * sizeof(float),
                       hipMemcpyDeviceToDevice, stream);
        hipLaunchKernelGGL(vq_mfma2, dim3(1024), dim3(256), 0, stream,
                           x, efrag, e2fp, pb1, pb2, pi1);
        hipLaunchKernelGGL(merge_kernel, dim3(256), dim3(256), 0, stream,
                           pb1, pb2, pi1, out, flagcnt, flaglist);
        hipLaunchKernelGGL(recheck, dim3(2048), dim3(256), 0, stream,
                           x, emb, flagcnt, flaglist, out);
        hipLaunchKernelGGL(gather_kernel, dim3(NROWS / 8), dim3(256), 0, stream,
                           emb, out + OFF_IND, out);
    } else {
        double* e2 = (double*)d_ws;
        hipLaunchKernelGGL(e2d_kernel, dim3(4096), dim3(256), 0, stream, emb, e2);
        hipMemcpyAsync(out + OFF_CNT, cnt, (size_t)G * M * sizeof(float),
                       hipMemcpyDeviceToDevice, stream);
        hipLaunchKernelGGL(argmin_kernel, dim3((NQ / QT) * G), dim3(256), 0, stream,
                           x, emb, e2, out);
        hipLaunchKernelGGL(gather_kernel, dim3(NROWS / 8), dim3(256), 0, stream,
                           emb, out + OFF_IND, out);
    }
}